// Round 9
// baseline (1235.190 us; speedup 1.0000x reference)
//
#include <hip/hip_runtime.h>
#include <hip/hip_bf16.h>

// ---------------------------------------------------------------------------
// Phase 1a: CSR build by dst, then gather-aggregate
// ---------------------------------------------------------------------------

__global__ __launch_bounds__(256) void sge_count(
    const int* __restrict__ dst, int* __restrict__ cnt, int nE) {
  int e = blockIdx.x * 256 + threadIdx.x;
  if (e >= nE) return;
  atomicAdd(&cnt[dst[e]], 1);
}

__global__ __launch_bounds__(256) void sge_blocksum(
    const int* __restrict__ cnt, int* __restrict__ bsum, int N) {
  int i = blockIdx.x * 256 + threadIdx.x;
  int v = (i < N) ? cnt[i] : 0;
#pragma unroll
  for (int o = 1; o < 64; o <<= 1) v += __shfl_xor(v, o);
  __shared__ int ws[4];
  int lane = threadIdx.x & 63, wid = threadIdx.x >> 6;
  if (lane == 0) ws[wid] = v;
  __syncthreads();
  if (threadIdx.x == 0)
    bsum[blockIdx.x] = ws[0] + ws[1] + ws[2] + ws[3];
}

__global__ __launch_bounds__(64) void sge_scan_top(
    int* __restrict__ bsum, int* __restrict__ offs, int nb, int N, int nE) {
  int lane = threadIdx.x;
  int carry = 0;
  for (int base = 0; base < nb; base += 64) {
    int i = base + lane;
    int v = (i < nb) ? bsum[i] : 0;
    int s = v;
#pragma unroll
    for (int o = 1; o < 64; o <<= 1) {
      int t = __shfl_up(s, o);
      if (lane >= o) s += t;
    }
    if (i < nb) bsum[i] = carry + s - v;  // exclusive
    carry += __shfl(s, 63);
  }
  if (lane == 0) offs[N] = nE;
}

__global__ __launch_bounds__(256) void sge_scan_block(
    const int* __restrict__ cnt, const int* __restrict__ bsum,
    int* __restrict__ offs, int* __restrict__ pos, int N) {
  int i = blockIdx.x * 256 + threadIdx.x;
  int v = (i < N) ? cnt[i] : 0;
  int lane = threadIdx.x & 63, wid = threadIdx.x >> 6;
  int s = v;
#pragma unroll
  for (int o = 1; o < 64; o <<= 1) {
    int t = __shfl_up(s, o);
    if (lane >= o) s += t;
  }
  __shared__ int ws[4];
  if (lane == 63) ws[wid] = s;
  __syncthreads();
  int wbase = 0;
  for (int w = 0; w < wid; ++w) wbase += ws[w];
  if (i < N) {
    int o = bsum[blockIdx.x] + wbase + s - v;
    offs[i] = o;
    pos[i] = o;
  }
}

__global__ __launch_bounds__(256) void sge_fill(
    const int* __restrict__ src, const int* __restrict__ dst,
    int* __restrict__ pos, int* __restrict__ sorted_src, int nE) {
  int e = blockIdx.x * 256 + threadIdx.x;
  if (e >= nE) return;
  int p = atomicAdd(&pos[dst[e]], 1);
  sorted_src[p] = src[e];
}

// 128 threads per node; 4-way unrolled independent accumulators
__global__ __launch_bounds__(256) void sge_gather(
    const float* __restrict__ x, const int* __restrict__ sorted_src,
    const int* __restrict__ offs, float* __restrict__ agg, int N) {
  int node = blockIdx.x * 2 + (threadIdx.x >> 7);
  int c = threadIdx.x & 127;
  if (node >= N) return;
  int e0 = offs[node], e1 = offs[node + 1];
  float a0 = 0.f, a1 = 0.f, a2 = 0.f, a3 = 0.f;
  int e = e0;
  for (; e + 4 <= e1; e += 4) {
    int s0 = sorted_src[e + 0];
    int s1 = sorted_src[e + 1];
    int s2 = sorted_src[e + 2];
    int s3 = sorted_src[e + 3];
    a0 += x[(size_t)s0 * 128 + c];
    a1 += x[(size_t)s1 * 128 + c];
    a2 += x[(size_t)s2 * 128 + c];
    a3 += x[(size_t)s3 * 128 + c];
  }
  for (; e < e1; ++e) a0 += x[(size_t)sorted_src[e] * 128 + c];
  float acc = (a0 + a1) + (a2 + a3);
  float dg = (float)(e1 - e0);
  agg[(size_t)node * 128 + c] = acc / fmaxf(dg, 1.0f);
}

// ---------------------------------------------------------------------------
// Phase 1b: z = agg @ W   [N,128]@[128,256] -> [N,256]
// ---------------------------------------------------------------------------
__global__ __launch_bounds__(256) void sge_gemm(
    const float* __restrict__ agg, const float* __restrict__ W,
    float* __restrict__ z) {
  __shared__ float xs[32][128];
  int n0 = blockIdx.x * 32;
  int t = threadIdx.x;
#pragma unroll
  for (int i = 0; i < 16; ++i) {
    int idx = t + i * 256;
    int r = idx >> 7;
    int c = idx & 127;
    xs[r][c] = agg[(long long)(n0 + r) * 128 + c];
  }
  __syncthreads();
  int wv = t >> 6, lane = t & 63;
  int r0 = wv * 8;
  float acc[8][4];
#pragma unroll
  for (int r = 0; r < 8; ++r)
#pragma unroll
    for (int q = 0; q < 4; ++q) acc[r][q] = 0.f;
  for (int k = 0; k < 128; k += 4) {
    float4 xv[8];
#pragma unroll
    for (int r = 0; r < 8; ++r) xv[r] = *(const float4*)&xs[r0 + r][k];
#pragma unroll
    for (int kk = 0; kk < 4; ++kk) {
      const float* Wr = W + (k + kk) * 256 + lane;
      float w0 = Wr[0], w1 = Wr[64], w2 = Wr[128], w3 = Wr[192];
#pragma unroll
      for (int r = 0; r < 8; ++r) {
        float xk = (kk == 0) ? xv[r].x
                 : (kk == 1) ? xv[r].y
                 : (kk == 2) ? xv[r].z : xv[r].w;
        acc[r][0] = fmaf(xk, w0, acc[r][0]);
        acc[r][1] = fmaf(xk, w1, acc[r][1]);
        acc[r][2] = fmaf(xk, w2, acc[r][2]);
        acc[r][3] = fmaf(xk, w3, acc[r][3]);
      }
    }
  }
#pragma unroll
  for (int r = 0; r < 8; ++r) {
    float* zr = z + (long long)(n0 + r0 + r) * 256 + lane;
#pragma unroll
    for (int q = 0; q < 4; ++q) zr[q * 64] = acc[r][q];
  }
}

// ---------------------------------------------------------------------------
// Phase 2 (v10): 256 threads per pair = 4 waves, one QUADRANT per wave:
//   w0: C_xy -> fab (h = gba from w1)   w1: C_yx -> gba (h = fab from w0)
//   w2: C_xx -> faa (h = own)           w3: C_yy -> gbb (h = own)
// lane = (row = l>>1 ... no: row = l&31 x2 halves) -> lane l: row = l>>1,
// colhalf = l&1, V[16] per lane  => live set ~45 regs, fits the 64-reg
// budget of launch_bounds(256,8) with NO AGPR parking / spill.
// Partner-lane (l^1) sum via DPP quad_perm; wave max via DPP row chain;
// E + wave-max through double-buffered LDS, ONE __syncthreads per iter.
// ---------------------------------------------------------------------------
template <int CTRL>
__device__ __forceinline__ float dpp_max(float x) {
  int r = __builtin_amdgcn_update_dpp(__float_as_int(x), __float_as_int(x),
                                      CTRL, 0xF, 0xF, false);
  return fmaxf(x, __int_as_float(r));
}
template <int CTRL>
__device__ __forceinline__ float dpp_add(float x) {
  int r = __builtin_amdgcn_update_dpp(0, __float_as_int(x), CTRL, 0xF, 0xF, true);
  return x + __int_as_float(r);
}

__global__ __launch_bounds__(256, 8) void sge_energy(
    const float* __restrict__ z, const int* __restrict__ ep,
    const int* __restrict__ en, float* __restrict__ out, int nP) {
  __shared__ __align__(16) float zbuf[512];      // zx[256] | zy[256]
  __shared__ __align__(16) float Ebuf[2][4][32]; // [buf][quad][col]
  __shared__ float mbuf[2][4];                   // [buf][quad] wave max
  __shared__ float red[4];

  int t = threadIdx.x;
  int w = t >> 6;         // quadrant 0:xy 1:yx 2:xx 3:yy
  int l = t & 63;
  int row = l >> 1;
  int ch = l & 1;         // column half: cols [16*ch, 16*ch+16)

  int pair = blockIdx.x;
  bool isPos = pair < nP;
  int idx = isPos ? pair : pair - nP;
  const int* E = isPos ? ep : en;
  int na = E[idx], nb = E[idx + nP];

  // stage both z rows: 512 floats, 256 threads x float2 (coalesced)
  {
    const float2* za = (const float2*)(z + (size_t)na * 256);
    const float2* zb = (const float2*)(z + (size_t)nb * 256);
    ((float2*)zbuf)[t] = (t < 128) ? za[t] : zb[t - 128];
  }
  __syncthreads();

  const float* zx = zbuf;
  const float* zy = zbuf + 256;
  bool rowIsX = (w == 0) || (w == 2);
  bool colIsX = (w == 1) || (w == 2);
  const float* zrow = (rowIsX ? zx : zy) + row * 8;
  const float* pcol = colIsX ? zx : zy;

  float xr[8];
  {
    float4 a0 = ((const float4*)zrow)[0];
    float4 a1 = ((const float4*)zrow)[1];
    xr[0] = a0.x; xr[1] = a0.y; xr[2] = a0.z; xr[3] = a0.w;
    xr[4] = a1.x; xr[5] = a1.y; xr[6] = a1.z; xr[7] = a1.w;
  }

  const float RLNE = 1.44269504088896340736f;  // log2(e)
  const float LN2 = 0.69314718055994530942f;
  const float LN32 = 3.46573590279972654709f;  // ln(32)
  const float K20 = RLNE / 10.0f;

  // build V[16] = 2^(-C*k2_0) for this lane's 16 columns
  float V[16];
#pragma unroll
  for (int jj = 0; jj < 16; ++jj) {
    int j = ch * 16 + jj;
    float4 a0 = ((const float4*)(pcol + j * 8))[0];
    float4 a1 = ((const float4*)(pcol + j * 8))[1];
    float d0 = xr[0] - a0.x, d1 = xr[1] - a0.y;
    float d2 = xr[2] - a0.z, d3 = xr[3] - a0.w;
    float d4 = xr[4] - a1.x, d5 = xr[5] - a1.y;
    float d6 = xr[6] - a1.z, d7 = xr[7] - a1.w;
    float sq = d0 * d0;
    sq = fmaf(d1, d1, sq); sq = fmaf(d2, d2, sq); sq = fmaf(d3, d3, sq);
    sq = fmaf(d4, d4, sq); sq = fmaf(d5, d5, sq); sq = fmaf(d6, d6, sq);
    sq = fmaf(d7, d7, sq);
    float C = __builtin_amdgcn_sqrtf(sq + 1e-8f);
    V[jj] = __builtin_amdgcn_exp2f(-C * K20);
  }

  int rq = (w == 0) ? 1 : (w == 1) ? 0 : w;  // quadrant whose E we read
  float P = 0.0f;
  float epsv = 10.0f;
  int cur = 0;

#pragma unroll 1
  for (int it = 0; it < 9; ++it) {
    float eps = (it == 8) ? 0.05f : epsv;
    float k2 = RLNE / eps;
    float eln2 = eps * LN2;
    float c32 = eps * LN32;

    if (it == 8) {
      // eps 0.078125 -> 0.05: exponent scales by 1.5625
#pragma unroll
      for (int jj = 0; jj < 16; ++jj)
        V[jj] = __builtin_amdgcn_exp2f(1.5625f * __builtin_amdgcn_logf(V[jj]));
    } else if (it > 0) {
#pragma unroll
      for (int jj = 0; jj < 16; ++jj) V[jj] *= V[jj];
    }

    // full-wave max of P (this wave's 32-row potential, rows duplicated x2)
    float m = P;
    m = dpp_max<0x111>(m);  // row_shr:1
    m = dpp_max<0x112>(m);  // row_shr:2
    m = dpp_max<0x114>(m);  // row_shr:4
    m = dpp_max<0x118>(m);  // row_shr:8
    m = dpp_max<0x142>(m);  // row_bcast15
    m = dpp_max<0x143>(m);  // row_bcast31 -> lane63 = wave max
    m = __int_as_float(__builtin_amdgcn_readlane(__float_as_int(m), 63));

    if (ch == 0) Ebuf[cur][w][row] = __builtin_amdgcn_exp2f((P - m) * k2);
    if (l == 0) mbuf[cur][w] = m;
    __syncthreads();

    float mRead = (w < 2) ? mbuf[cur][rq] : m;
    const float4* Er = (const float4*)(Ebuf[cur][rq] + ch * 16);
    float s0 = 0.f, s1 = 0.f, s2 = 0.f, s3 = 0.f;
#pragma unroll
    for (int jq = 0; jq < 4; ++jq) {
      float4 Ev = Er[jq];
      s0 = fmaf(Ev.x, V[4 * jq + 0], s0);
      s1 = fmaf(Ev.y, V[4 * jq + 1], s1);
      s2 = fmaf(Ev.z, V[4 * jq + 2], s2);
      s3 = fmaf(Ev.w, V[4 * jq + 3], s3);
    }
    float s = (s0 + s1) + (s2 + s3);
    // partner lane (l^1) holds the other 16 columns: DPP quad_perm [1,0,3,2]
    {
      int r = __builtin_amdgcn_update_dpp(0, __float_as_int(s), 0xB1, 0xF, 0xF,
                                          true);
      s += __int_as_float(r);
    }
    s = fmaxf(s, 1e-37f);

    P = 0.5f * (P + (c32 - mRead - eln2 * __builtin_amdgcn_logf(s)));
    cur ^= 1;
    epsv *= 0.5f;
  }

  // wave sum of P (each row counted twice); energy = (w0+w1-w2-w3)/64
  float d = P;
  d = dpp_add<0x111>(d);
  d = dpp_add<0x112>(d);
  d = dpp_add<0x114>(d);
  d = dpp_add<0x118>(d);
  d = dpp_add<0x142>(d);
  d = dpp_add<0x143>(d);  // lane63 = full-wave sum
  if (l == 63) red[w] = d;
  __syncthreads();
  if (t == 0) {
    float e = ((red[0] + red[1]) - (red[2] + red[3])) * (1.0f / 64.0f);
    float term;
    if (isPos) {
      term = e * e;
    } else {
      float mm = fmaxf(1.0f - e, 0.0f);
      term = mm * mm;
    }
    atomicAdd(out, term / (float)nP);
  }
}

// ---------------------------------------------------------------------------
extern "C" void kernel_launch(void* const* d_in, const int* in_sizes, int n_in,
                              void* d_out, int out_size, void* d_ws, size_t ws_size,
                              hipStream_t stream) {
  const float* x  = (const float*)d_in[0];
  const int*   ei = (const int*)d_in[1];
  const int*   ep = (const int*)d_in[2];
  const int*   en = (const int*)d_in[3];
  const float* W  = (const float*)d_in[4];
  float* out = (float*)d_out;

  int N  = in_sizes[0] / 128;   // 100000 nodes
  int nE = in_sizes[1] / 2;     // 1600000 edges
  int nP = in_sizes[2] / 2;     // 30000 pos (== neg)

  size_t zBytes   = (size_t)N * 256 * sizeof(float);
  size_t aggBytes = (size_t)N * 128 * sizeof(float);
  if (ws_size < zBytes + aggBytes) return;

  char* ws = (char*)d_ws;
  float* z   = (float*)ws;                 // written LAST (by gemm)
  float* agg = (float*)(ws + zBytes);

  // CSR temporaries overlaid inside the z region (dead before gemm)
  int* cnt        = (int*)ws;              // N
  int* offs       = cnt + N;               // N+1
  int* pos        = offs + N + 1;          // N
  int* bsum       = pos + N;               // <= 4096
  int* sorted_src = bsum + 4096;           // nE

  int nb = (N + 255) / 256;

  hipMemsetAsync(cnt, 0, (size_t)N * sizeof(int), stream);
  hipMemsetAsync(out, 0, sizeof(float) * out_size, stream);

  const int* src = ei;
  const int* dst = ei + nE;

  int eb = (nE + 255) / 256;
  sge_count<<<eb, 256, 0, stream>>>(dst, cnt, nE);
  sge_blocksum<<<nb, 256, 0, stream>>>(cnt, bsum, N);
  sge_scan_top<<<1, 64, 0, stream>>>(bsum, offs, nb, N, nE);
  sge_scan_block<<<nb, 256, 0, stream>>>(cnt, bsum, offs, pos, N);
  sge_fill<<<eb, 256, 0, stream>>>(src, dst, pos, sorted_src, nE);
  sge_gather<<<(N + 1) / 2, 256, 0, stream>>>(x, sorted_src, offs, agg, N);

  sge_gemm<<<(N + 31) / 32, 256, 0, stream>>>(agg, W, z);

  sge_energy<<<2 * nP, 256, 0, stream>>>(z, ep, en, out, nP);
}

// Round 10
// 1214.301 us; speedup vs baseline: 1.0172x; 1.0172x over previous
//
#include <hip/hip_runtime.h>
#include <hip/hip_bf16.h>

// ---------------------------------------------------------------------------
// Phase 1a: CSR build by dst, then gather-aggregate
// ---------------------------------------------------------------------------

__global__ __launch_bounds__(256) void sge_count(
    const int* __restrict__ dst, int* __restrict__ cnt, int nE) {
  int e = blockIdx.x * 256 + threadIdx.x;
  if (e >= nE) return;
  atomicAdd(&cnt[dst[e]], 1);
}

__global__ __launch_bounds__(256) void sge_blocksum(
    const int* __restrict__ cnt, int* __restrict__ bsum, int N) {
  int i = blockIdx.x * 256 + threadIdx.x;
  int v = (i < N) ? cnt[i] : 0;
#pragma unroll
  for (int o = 1; o < 64; o <<= 1) v += __shfl_xor(v, o);
  __shared__ int ws[4];
  int lane = threadIdx.x & 63, wid = threadIdx.x >> 6;
  if (lane == 0) ws[wid] = v;
  __syncthreads();
  if (threadIdx.x == 0)
    bsum[blockIdx.x] = ws[0] + ws[1] + ws[2] + ws[3];
}

__global__ __launch_bounds__(64) void sge_scan_top(
    int* __restrict__ bsum, int* __restrict__ offs, int nb, int N, int nE) {
  int lane = threadIdx.x;
  int carry = 0;
  for (int base = 0; base < nb; base += 64) {
    int i = base + lane;
    int v = (i < nb) ? bsum[i] : 0;
    int s = v;
#pragma unroll
    for (int o = 1; o < 64; o <<= 1) {
      int t = __shfl_up(s, o);
      if (lane >= o) s += t;
    }
    if (i < nb) bsum[i] = carry + s - v;  // exclusive
    carry += __shfl(s, 63);
  }
  if (lane == 0) offs[N] = nE;
}

__global__ __launch_bounds__(256) void sge_scan_block(
    const int* __restrict__ cnt, const int* __restrict__ bsum,
    int* __restrict__ offs, int* __restrict__ pos, int N) {
  int i = blockIdx.x * 256 + threadIdx.x;
  int v = (i < N) ? cnt[i] : 0;
  int lane = threadIdx.x & 63, wid = threadIdx.x >> 6;
  int s = v;
#pragma unroll
  for (int o = 1; o < 64; o <<= 1) {
    int t = __shfl_up(s, o);
    if (lane >= o) s += t;
  }
  __shared__ int ws[4];
  if (lane == 63) ws[wid] = s;
  __syncthreads();
  int wbase = 0;
  for (int w = 0; w < wid; ++w) wbase += ws[w];
  if (i < N) {
    int o = bsum[blockIdx.x] + wbase + s - v;
    offs[i] = o;
    pos[i] = o;
  }
}

__global__ __launch_bounds__(256) void sge_fill(
    const int* __restrict__ src, const int* __restrict__ dst,
    int* __restrict__ pos, int* __restrict__ sorted_src, int nE) {
  int e = blockIdx.x * 256 + threadIdx.x;
  if (e >= nE) return;
  int p = atomicAdd(&pos[dst[e]], 1);
  sorted_src[p] = src[e];
}

// 128 threads per node; 4-way unrolled independent accumulators
__global__ __launch_bounds__(256) void sge_gather(
    const float* __restrict__ x, const int* __restrict__ sorted_src,
    const int* __restrict__ offs, float* __restrict__ agg, int N) {
  int node = blockIdx.x * 2 + (threadIdx.x >> 7);
  int c = threadIdx.x & 127;
  if (node >= N) return;
  int e0 = offs[node], e1 = offs[node + 1];
  float a0 = 0.f, a1 = 0.f, a2 = 0.f, a3 = 0.f;
  int e = e0;
  for (; e + 4 <= e1; e += 4) {
    int s0 = sorted_src[e + 0];
    int s1 = sorted_src[e + 1];
    int s2 = sorted_src[e + 2];
    int s3 = sorted_src[e + 3];
    a0 += x[(size_t)s0 * 128 + c];
    a1 += x[(size_t)s1 * 128 + c];
    a2 += x[(size_t)s2 * 128 + c];
    a3 += x[(size_t)s3 * 128 + c];
  }
  for (; e < e1; ++e) a0 += x[(size_t)sorted_src[e] * 128 + c];
  float acc = (a0 + a1) + (a2 + a3);
  float dg = (float)(e1 - e0);
  agg[(size_t)node * 128 + c] = acc / fmaxf(dg, 1.0f);
}

// ---------------------------------------------------------------------------
// Phase 1b: z = agg @ W   [N,128]@[128,256] -> [N,256]
// ---------------------------------------------------------------------------
__global__ __launch_bounds__(256) void sge_gemm(
    const float* __restrict__ agg, const float* __restrict__ W,
    float* __restrict__ z) {
  __shared__ float xs[32][128];
  int n0 = blockIdx.x * 32;
  int t = threadIdx.x;
#pragma unroll
  for (int i = 0; i < 16; ++i) {
    int idx = t + i * 256;
    int r = idx >> 7;
    int c = idx & 127;
    xs[r][c] = agg[(long long)(n0 + r) * 128 + c];
  }
  __syncthreads();
  int wv = t >> 6, lane = t & 63;
  int r0 = wv * 8;
  float acc[8][4];
#pragma unroll
  for (int r = 0; r < 8; ++r)
#pragma unroll
    for (int q = 0; q < 4; ++q) acc[r][q] = 0.f;
  for (int k = 0; k < 128; k += 4) {
    float4 xv[8];
#pragma unroll
    for (int r = 0; r < 8; ++r) xv[r] = *(const float4*)&xs[r0 + r][k];
#pragma unroll
    for (int kk = 0; kk < 4; ++kk) {
      const float* Wr = W + (k + kk) * 256 + lane;
      float w0 = Wr[0], w1 = Wr[64], w2 = Wr[128], w3 = Wr[192];
#pragma unroll
      for (int r = 0; r < 8; ++r) {
        float xk = (kk == 0) ? xv[r].x
                 : (kk == 1) ? xv[r].y
                 : (kk == 2) ? xv[r].z : xv[r].w;
        acc[r][0] = fmaf(xk, w0, acc[r][0]);
        acc[r][1] = fmaf(xk, w1, acc[r][1]);
        acc[r][2] = fmaf(xk, w2, acc[r][2]);
        acc[r][3] = fmaf(xk, w3, acc[r][3]);
      }
    }
  }
#pragma unroll
  for (int r = 0; r < 8; ++r) {
    float* zr = z + (long long)(n0 + r0 + r) * 256 + lane;
#pragma unroll
    for (int q = 0; q < 4; ++q) zr[q * 64] = acc[r][q];
  }
}

// ---------------------------------------------------------------------------
// Phase 2 (v11): v9 structure (2 pairs/block, full 32-col row per lane,
// intra-wave exchange only, no block barriers in loop) with:
//   - NO max-reduction for iters 0..6 (eps >= 0.15625: |h-C|*k2 << 126,
//     LSE is shift-invariant so m=0 is exact in f32 range) -> critical path
//     per iter = exp -> LDS write -> LDS read -> dot -> log only.
//   - max chain kept for iters 7..8 (k2 = 18.5 / 28.9).
//   - launch_bounds(256,6): 85-reg budget fits the ~58-reg live set,
//     6 waves/SIMD instead of 4.
// ---------------------------------------------------------------------------
template <int CTRL>
__device__ __forceinline__ float dpp_max(float x) {
  int r = __builtin_amdgcn_update_dpp(__float_as_int(x), __float_as_int(x),
                                      CTRL, 0xF, 0xF, false);
  return fmaxf(x, __int_as_float(r));
}
template <int CTRL>
__device__ __forceinline__ float dpp_add(float x) {
  int r = __builtin_amdgcn_update_dpp(0, __float_as_int(x), CTRL, 0xF, 0xF, true);
  return x + __int_as_float(r);
}

__global__ __launch_bounds__(256, 6) void sge_energy(
    const float* __restrict__ z, const int* __restrict__ ep,
    const int* __restrict__ en, float* __restrict__ out, int nP) {
  __shared__ __align__(16) float zbuf[2][512];    // per pair: zx[256]|zy[256]
  __shared__ __align__(16) float Ebuf[2][2][64];  // per pair, per wave
  __shared__ float red[2][2];

  int t = threadIdx.x;
  int pl = t >> 7;        // pair-local index 0/1
  int tp = t & 127;       // thread within pair
  int w = tp >> 6;        // wave-in-pair: 0={xy,yx}, 1={xx,yy}
  int l = tp & 63;
  int row = l & 31;
  int own = l & 32;       // 0 = x-rows half, 32 = y-rows half

  int pair = blockIdx.x * 2 + pl;
  bool isPos = pair < nP;
  int idx = isPos ? pair : pair - nP;
  const int* E = isPos ? ep : en;
  int na = E[idx], nb = E[idx + nP];

  // stage both z rows of this pair (512 floats, 128 threads x float4)
  {
    const float4* za = (const float4*)(z + (size_t)na * 256);
    const float4* zb = (const float4*)(z + (size_t)nb * 256);
    ((float4*)zbuf[pl])[tp] = (tp < 64) ? za[tp] : zb[tp - 64];
  }
  __syncthreads();

  const float* zx = zbuf[pl];
  const float* zy = zbuf[pl] + 256;
  const float* zrow = (own ? zy : zx) + row * 8;
  bool colIsX = (w == 0) ? (own != 0) : (own == 0);
  const float* pcol = colIsX ? zx : zy;

  float xr[8];
  {
    float4 a0 = ((const float4*)zrow)[0];
    float4 a1 = ((const float4*)zrow)[1];
    xr[0] = a0.x; xr[1] = a0.y; xr[2] = a0.z; xr[3] = a0.w;
    xr[4] = a1.x; xr[5] = a1.y; xr[6] = a1.z; xr[7] = a1.w;
  }

  const float RLNE = 1.44269504088896340736f;  // log2(e)
  const float LN2 = 0.69314718055994530942f;
  const float LN32 = 3.46573590279972654709f;  // ln(32)
  const float K20 = RLNE / 10.0f;

  // build V = 2^(-C*k2_0) via direct squared distance
  float V[32];
#pragma unroll
  for (int j = 0; j < 32; ++j) {
    float4 a0 = ((const float4*)(pcol + j * 8))[0];
    float4 a1 = ((const float4*)(pcol + j * 8))[1];
    float d0 = xr[0] - a0.x, d1 = xr[1] - a0.y;
    float d2 = xr[2] - a0.z, d3 = xr[3] - a0.w;
    float d4 = xr[4] - a1.x, d5 = xr[5] - a1.y;
    float d6 = xr[6] - a1.z, d7 = xr[7] - a1.w;
    float sq = d0 * d0;
    sq = fmaf(d1, d1, sq); sq = fmaf(d2, d2, sq); sq = fmaf(d3, d3, sq);
    sq = fmaf(d4, d4, sq); sq = fmaf(d5, d5, sq); sq = fmaf(d6, d6, sq);
    sq = fmaf(d7, d7, sq);
    float C = __builtin_amdgcn_sqrtf(sq + 1e-8f);
    V[j] = __builtin_amdgcn_exp2f(-C * K20);
  }

  float* Ew = Ebuf[pl][w];
  int rb = (w == 0) ? (own ^ 32) : own;

  float P = 0.0f;
  float epsv = 10.0f;

#pragma unroll 1
  for (int it = 0; it < 9; ++it) {
    float eps = (it == 8) ? 0.05f : epsv;
    float k2 = RLNE / eps;
    float eln2 = eps * LN2;
    float c32 = eps * LN32;

    if (it == 8) {
      // eps 0.078125 -> 0.05: exponent scales by 1.5625
#pragma unroll
      for (int j = 0; j < 32; ++j)
        V[j] = __builtin_amdgcn_exp2f(1.5625f * __builtin_amdgcn_logf(V[j]));
    } else if (it > 0) {
#pragma unroll
      for (int j = 0; j < 32; ++j) V[j] *= V[j];
    }

    float mOwn, mRead;
    if (it >= 7) {
      // max needed only when k2 is large (eps <= 0.078125)
      float m = P;
      m = dpp_max<0x111>(m);  // row_shr:1
      m = dpp_max<0x112>(m);  // row_shr:2
      m = dpp_max<0x114>(m);  // row_shr:4
      m = dpp_max<0x118>(m);  // row_shr:8
      m = dpp_max<0x142>(m);  // row_bcast15 -> lanes 31/63 hold half maxes
      float g0 = __int_as_float(__builtin_amdgcn_readlane(__float_as_int(m), 31));
      float g1 = __int_as_float(__builtin_amdgcn_readlane(__float_as_int(m), 63));
      mOwn = own ? g1 : g0;
      mRead = (w == 0) ? (own ? g0 : g1) : mOwn;
    } else {
      mOwn = 0.0f;
      mRead = 0.0f;
    }

    Ew[l] = __builtin_amdgcn_exp2f((P - mOwn) * k2);
    __builtin_amdgcn_wave_barrier();

    float s0 = 0.f, s1 = 0.f, s2 = 0.f, s3 = 0.f;
#pragma unroll
    for (int jq = 0; jq < 8; ++jq) {
      float4 Ev = ((const float4*)(Ew + rb))[jq];
      s0 = fmaf(Ev.x, V[4 * jq + 0], s0);
      s1 = fmaf(Ev.y, V[4 * jq + 1], s1);
      s2 = fmaf(Ev.z, V[4 * jq + 2], s2);
      s3 = fmaf(Ev.w, V[4 * jq + 3], s3);
    }
    float s = fmaxf((s0 + s1) + (s2 + s3), 1e-37f);
    __builtin_amdgcn_wave_barrier();  // reads complete before next write

    P = 0.5f * (P + (c32 - mRead - eln2 * __builtin_amdgcn_logf(s)));
    epsv *= 0.5f;
  }

  // wave sums via DPP; energy = (sum_wave0 - sum_wave1)/32
  float d = P;
  d = dpp_add<0x111>(d);
  d = dpp_add<0x112>(d);
  d = dpp_add<0x114>(d);
  d = dpp_add<0x118>(d);
  d = dpp_add<0x142>(d);  // lane31 = sum(0..31), lane63 = sum(32..63)
  float s31 = __int_as_float(__builtin_amdgcn_readlane(__float_as_int(d), 31));
  float s63 = __int_as_float(__builtin_amdgcn_readlane(__float_as_int(d), 63));
  if (l == 0) red[pl][w] = s31 + s63;
  __syncthreads();
  if (tp == 0) {
    float e = (red[pl][0] - red[pl][1]) * (1.0f / 32.0f);
    float term;
    if (isPos) {
      term = e * e;
    } else {
      float mm = fmaxf(1.0f - e, 0.0f);
      term = mm * mm;
    }
    atomicAdd(out, term / (float)nP);
  }
}

// ---------------------------------------------------------------------------
extern "C" void kernel_launch(void* const* d_in, const int* in_sizes, int n_in,
                              void* d_out, int out_size, void* d_ws, size_t ws_size,
                              hipStream_t stream) {
  const float* x  = (const float*)d_in[0];
  const int*   ei = (const int*)d_in[1];
  const int*   ep = (const int*)d_in[2];
  const int*   en = (const int*)d_in[3];
  const float* W  = (const float*)d_in[4];
  float* out = (float*)d_out;

  int N  = in_sizes[0] / 128;   // 100000 nodes
  int nE = in_sizes[1] / 2;     // 1600000 edges
  int nP = in_sizes[2] / 2;     // 30000 pos (== neg)

  size_t zBytes   = (size_t)N * 256 * sizeof(float);
  size_t aggBytes = (size_t)N * 128 * sizeof(float);
  if (ws_size < zBytes + aggBytes) return;

  char* ws = (char*)d_ws;
  float* z   = (float*)ws;                 // written LAST (by gemm)
  float* agg = (float*)(ws + zBytes);

  // CSR temporaries overlaid inside the z region (dead before gemm)
  int* cnt        = (int*)ws;              // N
  int* offs       = cnt + N;               // N+1
  int* pos        = offs + N + 1;          // N
  int* bsum       = pos + N;               // <= 4096
  int* sorted_src = bsum + 4096;           // nE

  int nb = (N + 255) / 256;

  hipMemsetAsync(cnt, 0, (size_t)N * sizeof(int), stream);
  hipMemsetAsync(out, 0, sizeof(float) * out_size, stream);

  const int* src = ei;
  const int* dst = ei + nE;

  int eb = (nE + 255) / 256;
  sge_count<<<eb, 256, 0, stream>>>(dst, cnt, nE);
  sge_blocksum<<<nb, 256, 0, stream>>>(cnt, bsum, N);
  sge_scan_top<<<1, 64, 0, stream>>>(bsum, offs, nb, N, nE);
  sge_scan_block<<<nb, 256, 0, stream>>>(cnt, bsum, offs, pos, N);
  sge_fill<<<eb, 256, 0, stream>>>(src, dst, pos, sorted_src, nE);
  sge_gather<<<(N + 1) / 2, 256, 0, stream>>>(x, sorted_src, offs, agg, N);

  sge_gemm<<<(N + 31) / 32, 256, 0, stream>>>(agg, W, z);

  sge_energy<<<nP, 256, 0, stream>>>(z, ep, en, out, nP);
}

// Round 11
// 1185.575 us; speedup vs baseline: 1.0418x; 1.0242x over previous
//
#include <hip/hip_runtime.h>
#include <hip/hip_bf16.h>

// ---------------------------------------------------------------------------
// Phase 1a: CSR build by dst, then gather-aggregate
// ---------------------------------------------------------------------------

__global__ __launch_bounds__(256) void sge_count(
    const int* __restrict__ dst, int* __restrict__ cnt, int nE) {
  int e = blockIdx.x * 256 + threadIdx.x;
  if (e >= nE) return;
  atomicAdd(&cnt[dst[e]], 1);
}

__global__ __launch_bounds__(256) void sge_blocksum(
    const int* __restrict__ cnt, int* __restrict__ bsum, int N) {
  int i = blockIdx.x * 256 + threadIdx.x;
  int v = (i < N) ? cnt[i] : 0;
#pragma unroll
  for (int o = 1; o < 64; o <<= 1) v += __shfl_xor(v, o);
  __shared__ int ws[4];
  int lane = threadIdx.x & 63, wid = threadIdx.x >> 6;
  if (lane == 0) ws[wid] = v;
  __syncthreads();
  if (threadIdx.x == 0)
    bsum[blockIdx.x] = ws[0] + ws[1] + ws[2] + ws[3];
}

__global__ __launch_bounds__(64) void sge_scan_top(
    int* __restrict__ bsum, int* __restrict__ offs, int nb, int N, int nE) {
  int lane = threadIdx.x;
  int carry = 0;
  for (int base = 0; base < nb; base += 64) {
    int i = base + lane;
    int v = (i < nb) ? bsum[i] : 0;
    int s = v;
#pragma unroll
    for (int o = 1; o < 64; o <<= 1) {
      int t = __shfl_up(s, o);
      if (lane >= o) s += t;
    }
    if (i < nb) bsum[i] = carry + s - v;  // exclusive
    carry += __shfl(s, 63);
  }
  if (lane == 0) offs[N] = nE;
}

__global__ __launch_bounds__(256) void sge_scan_block(
    const int* __restrict__ cnt, const int* __restrict__ bsum,
    int* __restrict__ offs, int* __restrict__ pos, int N) {
  int i = blockIdx.x * 256 + threadIdx.x;
  int v = (i < N) ? cnt[i] : 0;
  int lane = threadIdx.x & 63, wid = threadIdx.x >> 6;
  int s = v;
#pragma unroll
  for (int o = 1; o < 64; o <<= 1) {
    int t = __shfl_up(s, o);
    if (lane >= o) s += t;
  }
  __shared__ int ws[4];
  if (lane == 63) ws[wid] = s;
  __syncthreads();
  int wbase = 0;
  for (int w = 0; w < wid; ++w) wbase += ws[w];
  if (i < N) {
    int o = bsum[blockIdx.x] + wbase + s - v;
    offs[i] = o;
    pos[i] = o;
  }
}

__global__ __launch_bounds__(256) void sge_fill(
    const int* __restrict__ src, const int* __restrict__ dst,
    int* __restrict__ pos, int* __restrict__ sorted_src, int nE) {
  int e = blockIdx.x * 256 + threadIdx.x;
  if (e >= nE) return;
  int p = atomicAdd(&pos[dst[e]], 1);
  sorted_src[p] = src[e];
}

// v2: 32 lanes per node, float4 per lane (512B coalesced per edge row),
// 8 nodes per 256-thread block, 2-way unrolled accumulators.
__global__ __launch_bounds__(256) void sge_gather(
    const float* __restrict__ x, const int* __restrict__ sorted_src,
    const int* __restrict__ offs, float* __restrict__ agg, int N) {
  int node = blockIdx.x * 8 + (threadIdx.x >> 5);
  int c4 = (threadIdx.x & 31) << 2;
  if (node >= N) return;
  int e0 = offs[node], e1 = offs[node + 1];
  float4 A = {0.f, 0.f, 0.f, 0.f}, B = {0.f, 0.f, 0.f, 0.f};
  int e = e0;
  for (; e + 2 <= e1; e += 2) {
    int s0 = sorted_src[e];
    int s1 = sorted_src[e + 1];
    float4 v0 = *(const float4*)&x[(size_t)s0 * 128 + c4];
    float4 v1 = *(const float4*)&x[(size_t)s1 * 128 + c4];
    A.x += v0.x; A.y += v0.y; A.z += v0.z; A.w += v0.w;
    B.x += v1.x; B.y += v1.y; B.z += v1.z; B.w += v1.w;
  }
  if (e < e1) {
    float4 v0 = *(const float4*)&x[(size_t)sorted_src[e] * 128 + c4];
    A.x += v0.x; A.y += v0.y; A.z += v0.z; A.w += v0.w;
  }
  float inv = 1.0f / fmaxf((float)(e1 - e0), 1.0f);
  float4 r;
  r.x = (A.x + B.x) * inv;
  r.y = (A.y + B.y) * inv;
  r.z = (A.z + B.z) * inv;
  r.w = (A.w + B.w) * inv;
  *(float4*)&agg[(size_t)node * 128 + c4] = r;
}

// ---------------------------------------------------------------------------
// Phase 1b: z = agg @ W   [N,128]@[128,256] -> [N,256]
// ---------------------------------------------------------------------------
__global__ __launch_bounds__(256) void sge_gemm(
    const float* __restrict__ agg, const float* __restrict__ W,
    float* __restrict__ z) {
  __shared__ float xs[32][128];
  int n0 = blockIdx.x * 32;
  int t = threadIdx.x;
#pragma unroll
  for (int i = 0; i < 16; ++i) {
    int idx = t + i * 256;
    int r = idx >> 7;
    int c = idx & 127;
    xs[r][c] = agg[(long long)(n0 + r) * 128 + c];
  }
  __syncthreads();
  int wv = t >> 6, lane = t & 63;
  int r0 = wv * 8;
  float acc[8][4];
#pragma unroll
  for (int r = 0; r < 8; ++r)
#pragma unroll
    for (int q = 0; q < 4; ++q) acc[r][q] = 0.f;
  for (int k = 0; k < 128; k += 4) {
    float4 xv[8];
#pragma unroll
    for (int r = 0; r < 8; ++r) xv[r] = *(const float4*)&xs[r0 + r][k];
#pragma unroll
    for (int kk = 0; kk < 4; ++kk) {
      const float* Wr = W + (k + kk) * 256 + lane;
      float w0 = Wr[0], w1 = Wr[64], w2 = Wr[128], w3 = Wr[192];
#pragma unroll
      for (int r = 0; r < 8; ++r) {
        float xk = (kk == 0) ? xv[r].x
                 : (kk == 1) ? xv[r].y
                 : (kk == 2) ? xv[r].z : xv[r].w;
        acc[r][0] = fmaf(xk, w0, acc[r][0]);
        acc[r][1] = fmaf(xk, w1, acc[r][1]);
        acc[r][2] = fmaf(xk, w2, acc[r][2]);
        acc[r][3] = fmaf(xk, w3, acc[r][3]);
      }
    }
  }
#pragma unroll
  for (int r = 0; r < 8; ++r) {
    float* zr = z + (long long)(n0 + r0 + r) * 256 + lane;
#pragma unroll
    for (int q = 0; q < 4; ++q) zr[q * 64] = acc[r][q];
  }
}

// ---------------------------------------------------------------------------
// Phase 2 (v12): v11 structure with
//   - norm-form cost build: C^2 = n_i + n_j - 2*dot  (9 VALU/entry vs 16;
//     matches the reference's own formula incl. max(.,0)+1e-8)
//   - C kept in registers -> iter-8 refresh is exp2(-C*k2_8): 32 trans,
//     not 64 (removes all 32 logs)
//   - launch_bounds(256,4): 128-reg budget fits the ~90-reg live set.
// ---------------------------------------------------------------------------
template <int CTRL>
__device__ __forceinline__ float dpp_max(float x) {
  int r = __builtin_amdgcn_update_dpp(__float_as_int(x), __float_as_int(x),
                                      CTRL, 0xF, 0xF, false);
  return fmaxf(x, __int_as_float(r));
}
template <int CTRL>
__device__ __forceinline__ float dpp_add(float x) {
  int r = __builtin_amdgcn_update_dpp(0, __float_as_int(x), CTRL, 0xF, 0xF, true);
  return x + __int_as_float(r);
}

__global__ __launch_bounds__(256, 4) void sge_energy(
    const float* __restrict__ z, const int* __restrict__ ep,
    const int* __restrict__ en, float* __restrict__ out, int nP) {
  __shared__ __align__(16) float zbuf[2][512];    // per pair: zx[256]|zy[256]
  __shared__ __align__(16) float nrm[2][64];      // per pair: nx[32]|ny[32]
  __shared__ __align__(16) float Ebuf[2][2][64];  // per pair, per wave
  __shared__ float red[2][2];

  int t = threadIdx.x;
  int pl = t >> 7;        // pair-local index 0/1
  int tp = t & 127;       // thread within pair
  int w = tp >> 6;        // wave-in-pair: 0={xy,yx}, 1={xx,yy}
  int l = tp & 63;
  int row = l & 31;
  int own = l & 32;       // 0 = x-rows half, 32 = y-rows half

  int pair = blockIdx.x * 2 + pl;
  bool isPos = pair < nP;
  int idx = isPos ? pair : pair - nP;
  const int* E = isPos ? ep : en;
  int na = E[idx], nb = E[idx + nP];

  // stage both z rows of this pair (512 floats, 128 threads x float4)
  {
    const float4* za = (const float4*)(z + (size_t)na * 256);
    const float4* zb = (const float4*)(z + (size_t)nb * 256);
    ((float4*)zbuf[pl])[tp] = (tp < 64) ? za[tp] : zb[tp - 64];
  }
  __syncthreads();
  if (tp < 64) {
    const float* zr = zbuf[pl] + tp * 8;
    float s = 0.0f;
#pragma unroll
    for (int d = 0; d < 8; ++d) s += zr[d] * zr[d];
    nrm[pl][tp] = s;
  }
  __syncthreads();

  const float* zx = zbuf[pl];
  const float* zy = zbuf[pl] + 256;
  const float* zrow = (own ? zy : zx) + row * 8;
  bool colIsX = (w == 0) ? (own != 0) : (own == 0);
  const float* pcol = colIsX ? zx : zy;
  const float* pn = colIsX ? nrm[pl] : (nrm[pl] + 32);
  float nself = nrm[pl][own + row];

  float xr[8];
  {
    float4 a0 = ((const float4*)zrow)[0];
    float4 a1 = ((const float4*)zrow)[1];
    xr[0] = a0.x; xr[1] = a0.y; xr[2] = a0.z; xr[3] = a0.w;
    xr[4] = a1.x; xr[5] = a1.y; xr[6] = a1.z; xr[7] = a1.w;
  }

  const float RLNE = 1.44269504088896340736f;  // log2(e)
  const float LN2 = 0.69314718055994530942f;
  const float LN32 = 3.46573590279972654709f;  // ln(32)
  const float K20 = RLNE / 10.0f;
  const float NK28 = -RLNE / 0.05f;            // -k2 at final eps

  // build: C (kept) and V = 2^(-C*k2_0); norm-form distance
  float C[32], V[32];
#pragma unroll
  for (int jq = 0; jq < 8; ++jq) {
    float4 n4 = ((const float4*)pn)[jq];
#pragma unroll
    for (int k = 0; k < 4; ++k) {
      int j = jq * 4 + k;
      float4 a0 = ((const float4*)(pcol + j * 8))[0];
      float4 a1 = ((const float4*)(pcol + j * 8))[1];
      float d = xr[0] * a0.x;
      d = fmaf(xr[1], a0.y, d); d = fmaf(xr[2], a0.z, d);
      d = fmaf(xr[3], a0.w, d); d = fmaf(xr[4], a1.x, d);
      d = fmaf(xr[5], a1.y, d); d = fmaf(xr[6], a1.z, d);
      d = fmaf(xr[7], a1.w, d);
      float nj = (k == 0) ? n4.x : (k == 1) ? n4.y : (k == 2) ? n4.z : n4.w;
      float sq = fmaf(-2.0f, d, nself + nj);
      float Cv = __builtin_amdgcn_sqrtf(fmaxf(sq, 0.0f) + 1e-8f);
      C[j] = Cv;
      V[j] = __builtin_amdgcn_exp2f(-Cv * K20);
    }
  }

  float* Ew = Ebuf[pl][w];
  int rb = (w == 0) ? (own ^ 32) : own;

  float P = 0.0f;
  float epsv = 10.0f;

#pragma unroll 1
  for (int it = 0; it < 9; ++it) {
    float eps = (it == 8) ? 0.05f : epsv;
    float k2 = RLNE / eps;
    float eln2 = eps * LN2;
    float c32 = eps * LN32;

    if (it == 8) {
      // fresh exponentials for the off-schedule final eps (no logs needed)
#pragma unroll
      for (int j = 0; j < 32; ++j)
        V[j] = __builtin_amdgcn_exp2f(C[j] * NK28);
    } else if (it > 0) {
#pragma unroll
      for (int j = 0; j < 32; ++j) V[j] *= V[j];
    }

    float mOwn, mRead;
    if (it >= 7) {
      float m = P;
      m = dpp_max<0x111>(m);  // row_shr:1
      m = dpp_max<0x112>(m);  // row_shr:2
      m = dpp_max<0x114>(m);  // row_shr:4
      m = dpp_max<0x118>(m);  // row_shr:8
      m = dpp_max<0x142>(m);  // row_bcast15 -> lanes 31/63 hold half maxes
      float g0 = __int_as_float(__builtin_amdgcn_readlane(__float_as_int(m), 31));
      float g1 = __int_as_float(__builtin_amdgcn_readlane(__float_as_int(m), 63));
      mOwn = own ? g1 : g0;
      mRead = (w == 0) ? (own ? g0 : g1) : mOwn;
    } else {
      mOwn = 0.0f;
      mRead = 0.0f;
    }

    Ew[l] = __builtin_amdgcn_exp2f((P - mOwn) * k2);
    __builtin_amdgcn_wave_barrier();

    float s0 = 0.f, s1 = 0.f, s2 = 0.f, s3 = 0.f;
#pragma unroll
    for (int jq = 0; jq < 8; ++jq) {
      float4 Ev = ((const float4*)(Ew + rb))[jq];
      s0 = fmaf(Ev.x, V[4 * jq + 0], s0);
      s1 = fmaf(Ev.y, V[4 * jq + 1], s1);
      s2 = fmaf(Ev.z, V[4 * jq + 2], s2);
      s3 = fmaf(Ev.w, V[4 * jq + 3], s3);
    }
    float s = fmaxf((s0 + s1) + (s2 + s3), 1e-37f);
    __builtin_amdgcn_wave_barrier();  // reads complete before next write

    P = 0.5f * (P + (c32 - mRead - eln2 * __builtin_amdgcn_logf(s)));
    epsv *= 0.5f;
  }

  // wave sums via DPP; energy = (sum_wave0 - sum_wave1)/32
  float d = P;
  d = dpp_add<0x111>(d);
  d = dpp_add<0x112>(d);
  d = dpp_add<0x114>(d);
  d = dpp_add<0x118>(d);
  d = dpp_add<0x142>(d);  // lane31 = sum(0..31), lane63 = sum(32..63)
  float s31 = __int_as_float(__builtin_amdgcn_readlane(__float_as_int(d), 31));
  float s63 = __int_as_float(__builtin_amdgcn_readlane(__float_as_int(d), 63));
  if (l == 0) red[pl][w] = s31 + s63;
  __syncthreads();
  if (tp == 0) {
    float e = (red[pl][0] - red[pl][1]) * (1.0f / 32.0f);
    float term;
    if (isPos) {
      term = e * e;
    } else {
      float mm = fmaxf(1.0f - e, 0.0f);
      term = mm * mm;
    }
    atomicAdd(out, term / (float)nP);
  }
}

// ---------------------------------------------------------------------------
extern "C" void kernel_launch(void* const* d_in, const int* in_sizes, int n_in,
                              void* d_out, int out_size, void* d_ws, size_t ws_size,
                              hipStream_t stream) {
  const float* x  = (const float*)d_in[0];
  const int*   ei = (const int*)d_in[1];
  const int*   ep = (const int*)d_in[2];
  const int*   en = (const int*)d_in[3];
  const float* W  = (const float*)d_in[4];
  float* out = (float*)d_out;

  int N  = in_sizes[0] / 128;   // 100000 nodes
  int nE = in_sizes[1] / 2;     // 1600000 edges
  int nP = in_sizes[2] / 2;     // 30000 pos (== neg)

  size_t zBytes   = (size_t)N * 256 * sizeof(float);
  size_t aggBytes = (size_t)N * 128 * sizeof(float);
  if (ws_size < zBytes + aggBytes) return;

  char* ws = (char*)d_ws;
  float* z   = (float*)ws;                 // written LAST (by gemm)
  float* agg = (float*)(ws + zBytes);

  // CSR temporaries overlaid inside the z region (dead before gemm)
  int* cnt        = (int*)ws;              // N
  int* offs       = cnt + N;               // N+1
  int* pos        = offs + N + 1;          // N
  int* bsum       = pos + N;               // <= 4096
  int* sorted_src = bsum + 4096;           // nE

  int nb = (N + 255) / 256;

  hipMemsetAsync(cnt, 0, (size_t)N * sizeof(int), stream);
  hipMemsetAsync(out, 0, sizeof(float) * out_size, stream);

  const int* src = ei;
  const int* dst = ei + nE;

  int eb = (nE + 255) / 256;
  sge_count<<<eb, 256, 0, stream>>>(dst, cnt, nE);
  sge_blocksum<<<nb, 256, 0, stream>>>(cnt, bsum, N);
  sge_scan_top<<<1, 64, 0, stream>>>(bsum, offs, nb, N, nE);
  sge_scan_block<<<nb, 256, 0, stream>>>(cnt, bsum, offs, pos, N);
  sge_fill<<<eb, 256, 0, stream>>>(src, dst, pos, sorted_src, nE);
  sge_gather<<<(N + 7) / 8, 256, 0, stream>>>(x, sorted_src, offs, agg, N);

  sge_gemm<<<(N + 31) / 32, 256, 0, stream>>>(agg, W, z);

  sge_energy<<<nP, 256, 0, stream>>>(z, ep, en, out, nP);
}

// Round 12
// 686.961 us; speedup vs baseline: 1.7980x; 1.7258x over previous
//
#include <hip/hip_runtime.h>
#include <hip/hip_bf16.h>

// ---------------------------------------------------------------------------
// Phase 1a: CSR build by dst, then gather-aggregate
// ---------------------------------------------------------------------------

__global__ __launch_bounds__(256) void sge_count(
    const int* __restrict__ dst, int* __restrict__ cnt, int nE) {
  int e = blockIdx.x * 256 + threadIdx.x;
  if (e >= nE) return;
  atomicAdd(&cnt[dst[e]], 1);
}

__global__ __launch_bounds__(256) void sge_blocksum(
    const int* __restrict__ cnt, int* __restrict__ bsum, int N) {
  int i = blockIdx.x * 256 + threadIdx.x;
  int v = (i < N) ? cnt[i] : 0;
#pragma unroll
  for (int o = 1; o < 64; o <<= 1) v += __shfl_xor(v, o);
  __shared__ int ws[4];
  int lane = threadIdx.x & 63, wid = threadIdx.x >> 6;
  if (lane == 0) ws[wid] = v;
  __syncthreads();
  if (threadIdx.x == 0)
    bsum[blockIdx.x] = ws[0] + ws[1] + ws[2] + ws[3];
}

__global__ __launch_bounds__(64) void sge_scan_top(
    int* __restrict__ bsum, int* __restrict__ offs, int nb, int N, int nE) {
  int lane = threadIdx.x;
  int carry = 0;
  for (int base = 0; base < nb; base += 64) {
    int i = base + lane;
    int v = (i < nb) ? bsum[i] : 0;
    int s = v;
#pragma unroll
    for (int o = 1; o < 64; o <<= 1) {
      int t = __shfl_up(s, o);
      if (lane >= o) s += t;
    }
    if (i < nb) bsum[i] = carry + s - v;  // exclusive
    carry += __shfl(s, 63);
  }
  if (lane == 0) offs[N] = nE;
}

__global__ __launch_bounds__(256) void sge_scan_block(
    const int* __restrict__ cnt, const int* __restrict__ bsum,
    int* __restrict__ offs, int* __restrict__ pos, int N) {
  int i = blockIdx.x * 256 + threadIdx.x;
  int v = (i < N) ? cnt[i] : 0;
  int lane = threadIdx.x & 63, wid = threadIdx.x >> 6;
  int s = v;
#pragma unroll
  for (int o = 1; o < 64; o <<= 1) {
    int t = __shfl_up(s, o);
    if (lane >= o) s += t;
  }
  __shared__ int ws[4];
  if (lane == 63) ws[wid] = s;
  __syncthreads();
  int wbase = 0;
  for (int w = 0; w < wid; ++w) wbase += ws[w];
  if (i < N) {
    int o = bsum[blockIdx.x] + wbase + s - v;
    offs[i] = o;
    pos[i] = o;
  }
}

__global__ __launch_bounds__(256) void sge_fill(
    const int* __restrict__ src, const int* __restrict__ dst,
    int* __restrict__ pos, int* __restrict__ sorted_src, int nE) {
  int e = blockIdx.x * 256 + threadIdx.x;
  if (e >= nE) return;
  int p = atomicAdd(&pos[dst[e]], 1);
  sorted_src[p] = src[e];
}

// 32 lanes per node, float4 per lane, 8 nodes per block
__global__ __launch_bounds__(256) void sge_gather(
    const float* __restrict__ x, const int* __restrict__ sorted_src,
    const int* __restrict__ offs, float* __restrict__ agg, int N) {
  int node = blockIdx.x * 8 + (threadIdx.x >> 5);
  int c4 = (threadIdx.x & 31) << 2;
  if (node >= N) return;
  int e0 = offs[node], e1 = offs[node + 1];
  float4 A = {0.f, 0.f, 0.f, 0.f}, B = {0.f, 0.f, 0.f, 0.f};
  int e = e0;
  for (; e + 2 <= e1; e += 2) {
    int s0 = sorted_src[e];
    int s1 = sorted_src[e + 1];
    float4 v0 = *(const float4*)&x[(size_t)s0 * 128 + c4];
    float4 v1 = *(const float4*)&x[(size_t)s1 * 128 + c4];
    A.x += v0.x; A.y += v0.y; A.z += v0.z; A.w += v0.w;
    B.x += v1.x; B.y += v1.y; B.z += v1.z; B.w += v1.w;
  }
  if (e < e1) {
    float4 v0 = *(const float4*)&x[(size_t)sorted_src[e] * 128 + c4];
    A.x += v0.x; A.y += v0.y; A.z += v0.z; A.w += v0.w;
  }
  float inv = 1.0f / fmaxf((float)(e1 - e0), 1.0f);
  float4 r;
  r.x = (A.x + B.x) * inv;
  r.y = (A.y + B.y) * inv;
  r.z = (A.z + B.z) * inv;
  r.w = (A.w + B.w) * inv;
  *(float4*)&agg[(size_t)node * 128 + c4] = r;
}

// ---------------------------------------------------------------------------
// Phase 1b: z = agg @ W   [N,128]@[128,256] -> [N,256]
// ---------------------------------------------------------------------------
__global__ __launch_bounds__(256) void sge_gemm(
    const float* __restrict__ agg, const float* __restrict__ W,
    float* __restrict__ z) {
  __shared__ float xs[32][128];
  int n0 = blockIdx.x * 32;
  int t = threadIdx.x;
#pragma unroll
  for (int i = 0; i < 16; ++i) {
    int idx = t + i * 256;
    int r = idx >> 7;
    int c = idx & 127;
    xs[r][c] = agg[(long long)(n0 + r) * 128 + c];
  }
  __syncthreads();
  int wv = t >> 6, lane = t & 63;
  int r0 = wv * 8;
  float acc[8][4];
#pragma unroll
  for (int r = 0; r < 8; ++r)
#pragma unroll
    for (int q = 0; q < 4; ++q) acc[r][q] = 0.f;
  for (int k = 0; k < 128; k += 4) {
    float4 xv[8];
#pragma unroll
    for (int r = 0; r < 8; ++r) xv[r] = *(const float4*)&xs[r0 + r][k];
#pragma unroll
    for (int kk = 0; kk < 4; ++kk) {
      const float* Wr = W + (k + kk) * 256 + lane;
      float w0 = Wr[0], w1 = Wr[64], w2 = Wr[128], w3 = Wr[192];
#pragma unroll
      for (int r = 0; r < 8; ++r) {
        float xk = (kk == 0) ? xv[r].x
                 : (kk == 1) ? xv[r].y
                 : (kk == 2) ? xv[r].z : xv[r].w;
        acc[r][0] = fmaf(xk, w0, acc[r][0]);
        acc[r][1] = fmaf(xk, w1, acc[r][1]);
        acc[r][2] = fmaf(xk, w2, acc[r][2]);
        acc[r][3] = fmaf(xk, w3, acc[r][3]);
      }
    }
  }
#pragma unroll
  for (int r = 0; r < 8; ++r) {
    float* zr = z + (long long)(n0 + r0 + r) * 256 + lane;
#pragma unroll
    for (int q = 0; q < 4; ++q) zr[q * 64] = acc[r][q];
  }
}

// ---------------------------------------------------------------------------
// Phase 2 (v13): DS-pipe diet + no contended atomics.
//  - Build reads row + 32 columns DIRECTLY from global (L2/L3-resident z;
//    column addresses half-wave-uniform -> 1-2 lines per instr). No zbuf
//    staging, no norm phase: LDS instr/wave drops ~155 -> ~82 (only the
//    9-iter E exchange remains on the DS pipe).
//  - Per-block partial sums written to ws (dead agg region); single-block
//    reduce kernel produces out. Removes 60000 same-address fp32 atomics.
// ---------------------------------------------------------------------------
template <int CTRL>
__device__ __forceinline__ float dpp_max(float x) {
  int r = __builtin_amdgcn_update_dpp(__float_as_int(x), __float_as_int(x),
                                      CTRL, 0xF, 0xF, false);
  return fmaxf(x, __int_as_float(r));
}
template <int CTRL>
__device__ __forceinline__ float dpp_add(float x) {
  int r = __builtin_amdgcn_update_dpp(0, __float_as_int(x), CTRL, 0xF, 0xF, true);
  return x + __int_as_float(r);
}

__global__ __launch_bounds__(256, 4) void sge_energy(
    const float* __restrict__ z, const int* __restrict__ ep,
    const int* __restrict__ en, float* __restrict__ partial, int nP) {
  __shared__ __align__(16) float Ebuf[2][2][64];  // [pair][wave][64]
  __shared__ float red[2][2];

  int t = threadIdx.x;
  int pl = t >> 7;        // pair-local index 0/1
  int tp = t & 127;       // thread within pair
  int w = tp >> 6;        // wave-in-pair: 0={xy,yx}, 1={xx,yy}
  int l = tp & 63;
  int row = l & 31;
  int own = l & 32;       // 0 = x-rows half, 32 = y-rows half

  int pair = blockIdx.x * 2 + pl;
  bool isPos = pair < nP;
  int idx = isPos ? pair : pair - nP;
  const int* E = isPos ? ep : en;
  int na = E[idx], nb = E[idx + nP];

  // own row straight from global
  const float* zrow = z + (size_t)(own ? nb : na) * 256 + row * 8;
  float4 r0 = ((const float4*)zrow)[0];
  float4 r1 = ((const float4*)zrow)[1];
  float xr[8];
  xr[0] = r0.x; xr[1] = r0.y; xr[2] = r0.z; xr[3] = r0.w;
  xr[4] = r1.x; xr[5] = r1.y; xr[6] = r1.z; xr[7] = r1.w;

  bool colIsX = (w == 0) ? (own != 0) : (own == 0);
  const float4* zc = (const float4*)(z + (size_t)(colIsX ? na : nb) * 256);

  const float RLNE = 1.44269504088896340736f;  // log2(e)
  const float LN2 = 0.69314718055994530942f;
  const float LN32 = 3.46573590279972654709f;  // ln(32)
  const float K20 = RLNE / 10.0f;
  const float NK28 = -RLNE / 0.05f;            // -k2 at final eps

  // build C (kept) and V = 2^(-C*k2_0); direct-difference distance;
  // 4-column load window (8 float4) to bound register pressure
  float C[32], V[32];
#pragma unroll
  for (int jq = 0; jq < 8; ++jq) {
    float4 a[8];
#pragma unroll
    for (int k = 0; k < 4; ++k) {
      a[2 * k] = zc[8 * jq + 2 * k];
      a[2 * k + 1] = zc[8 * jq + 2 * k + 1];
    }
#pragma unroll
    for (int k = 0; k < 4; ++k) {
      int j = jq * 4 + k;
      float4 a0 = a[2 * k], a1 = a[2 * k + 1];
      float d0 = xr[0] - a0.x, d1 = xr[1] - a0.y;
      float d2 = xr[2] - a0.z, d3 = xr[3] - a0.w;
      float d4 = xr[4] - a1.x, d5 = xr[5] - a1.y;
      float d6 = xr[6] - a1.z, d7 = xr[7] - a1.w;
      float sq = d0 * d0;
      sq = fmaf(d1, d1, sq); sq = fmaf(d2, d2, sq); sq = fmaf(d3, d3, sq);
      sq = fmaf(d4, d4, sq); sq = fmaf(d5, d5, sq); sq = fmaf(d6, d6, sq);
      sq = fmaf(d7, d7, sq);
      float Cv = __builtin_amdgcn_sqrtf(sq + 1e-8f);
      C[j] = Cv;
      V[j] = __builtin_amdgcn_exp2f(-Cv * K20);
    }
  }

  float* Ew = Ebuf[pl][w];
  int rb = (w == 0) ? (own ^ 32) : own;

  float P = 0.0f;
  float epsv = 10.0f;

#pragma unroll 1
  for (int it = 0; it < 9; ++it) {
    float eps = (it == 8) ? 0.05f : epsv;
    float k2 = RLNE / eps;
    float eln2 = eps * LN2;
    float c32 = eps * LN32;

    if (it == 8) {
#pragma unroll
      for (int j = 0; j < 32; ++j)
        V[j] = __builtin_amdgcn_exp2f(C[j] * NK28);
    } else if (it > 0) {
#pragma unroll
      for (int j = 0; j < 32; ++j) V[j] *= V[j];
    }

    float mOwn, mRead;
    if (it >= 7) {
      float m = P;
      m = dpp_max<0x111>(m);
      m = dpp_max<0x112>(m);
      m = dpp_max<0x114>(m);
      m = dpp_max<0x118>(m);
      m = dpp_max<0x142>(m);  // lanes 31/63 hold half maxes
      float g0 = __int_as_float(__builtin_amdgcn_readlane(__float_as_int(m), 31));
      float g1 = __int_as_float(__builtin_amdgcn_readlane(__float_as_int(m), 63));
      mOwn = own ? g1 : g0;
      mRead = (w == 0) ? (own ? g0 : g1) : mOwn;
    } else {
      mOwn = 0.0f;
      mRead = 0.0f;
    }

    Ew[l] = __builtin_amdgcn_exp2f((P - mOwn) * k2);
    __builtin_amdgcn_wave_barrier();

    float s0 = 0.f, s1 = 0.f, s2 = 0.f, s3 = 0.f;
#pragma unroll
    for (int jq = 0; jq < 8; ++jq) {
      float4 Ev = ((const float4*)(Ew + rb))[jq];
      s0 = fmaf(Ev.x, V[4 * jq + 0], s0);
      s1 = fmaf(Ev.y, V[4 * jq + 1], s1);
      s2 = fmaf(Ev.z, V[4 * jq + 2], s2);
      s3 = fmaf(Ev.w, V[4 * jq + 3], s3);
    }
    float s = fmaxf((s0 + s1) + (s2 + s3), 1e-37f);
    __builtin_amdgcn_wave_barrier();  // reads complete before next write

    P = 0.5f * (P + (c32 - mRead - eln2 * __builtin_amdgcn_logf(s)));
    epsv *= 0.5f;
  }

  // wave sums via DPP
  float d = P;
  d = dpp_add<0x111>(d);
  d = dpp_add<0x112>(d);
  d = dpp_add<0x114>(d);
  d = dpp_add<0x118>(d);
  d = dpp_add<0x142>(d);
  float s31 = __int_as_float(__builtin_amdgcn_readlane(__float_as_int(d), 31));
  float s63 = __int_as_float(__builtin_amdgcn_readlane(__float_as_int(d), 63));
  if (l == 0) red[pl][w] = s31 + s63;
  __syncthreads();
  if (t == 0) {
    float tot = 0.0f;
#pragma unroll
    for (int q = 0; q < 2; ++q) {
      int pr = blockIdx.x * 2 + q;
      float e = (red[q][0] - red[q][1]) * (1.0f / 32.0f);
      float term;
      if (pr < nP) {
        term = e * e;
      } else {
        float mm = fmaxf(1.0f - e, 0.0f);
        term = mm * mm;
      }
      tot += term;
    }
    partial[blockIdx.x] = tot;   // no atomics: per-block partial
  }
}

// single-block final reduction: out = sum(partial) / nP
__global__ __launch_bounds__(1024) void sge_reduce(
    const float* __restrict__ partial, int n, float invnP,
    float* __restrict__ out) {
  __shared__ float ws[16];
  float s = 0.0f;
  for (int i = threadIdx.x; i < n; i += 1024) s += partial[i];
#pragma unroll
  for (int o = 1; o < 64; o <<= 1) s += __shfl_xor(s, o);
  if ((threadIdx.x & 63) == 0) ws[threadIdx.x >> 6] = s;
  __syncthreads();
  if (threadIdx.x == 0) {
    float tt = 0.0f;
#pragma unroll
    for (int q = 0; q < 16; ++q) tt += ws[q];
    out[0] = tt * invnP;
  }
}

// ---------------------------------------------------------------------------
extern "C" void kernel_launch(void* const* d_in, const int* in_sizes, int n_in,
                              void* d_out, int out_size, void* d_ws, size_t ws_size,
                              hipStream_t stream) {
  const float* x  = (const float*)d_in[0];
  const int*   ei = (const int*)d_in[1];
  const int*   ep = (const int*)d_in[2];
  const int*   en = (const int*)d_in[3];
  const float* W  = (const float*)d_in[4];
  float* out = (float*)d_out;

  int N  = in_sizes[0] / 128;   // 100000 nodes
  int nE = in_sizes[1] / 2;     // 1600000 edges
  int nP = in_sizes[2] / 2;     // 30000 pos (== neg)

  size_t zBytes   = (size_t)N * 256 * sizeof(float);
  size_t aggBytes = (size_t)N * 128 * sizeof(float);
  if (ws_size < zBytes + aggBytes) return;

  char* ws = (char*)d_ws;
  float* z   = (float*)ws;                 // written LAST (by gemm)
  float* agg = (float*)(ws + zBytes);

  // CSR temporaries overlaid inside the z region (dead before gemm)
  int* cnt        = (int*)ws;              // N
  int* offs       = cnt + N;               // N+1
  int* pos        = offs + N + 1;          // N
  int* bsum       = pos + N;               // <= 4096
  int* sorted_src = bsum + 4096;           // nE

  // per-block partials overlaid in the agg region (dead after gemm)
  float* partial = agg;                    // nP floats

  int nb = (N + 255) / 256;

  hipMemsetAsync(cnt, 0, (size_t)N * sizeof(int), stream);

  const int* src = ei;
  const int* dst = ei + nE;

  int eb = (nE + 255) / 256;
  sge_count<<<eb, 256, 0, stream>>>(dst, cnt, nE);
  sge_blocksum<<<nb, 256, 0, stream>>>(cnt, bsum, N);
  sge_scan_top<<<1, 64, 0, stream>>>(bsum, offs, nb, N, nE);
  sge_scan_block<<<nb, 256, 0, stream>>>(cnt, bsum, offs, pos, N);
  sge_fill<<<eb, 256, 0, stream>>>(src, dst, pos, sorted_src, nE);
  sge_gather<<<(N + 7) / 8, 256, 0, stream>>>(x, sorted_src, offs, agg, N);

  sge_gemm<<<(N + 31) / 32, 256, 0, stream>>>(agg, W, z);

  sge_energy<<<nP, 256, 0, stream>>>(z, ep, en, partial, nP);
  sge_reduce<<<1, 1024, 0, stream>>>(partial, nP, 1.0f / (float)nP, out);
}

// Round 13
// 686.912 us; speedup vs baseline: 1.7982x; 1.0001x over previous
//
#include <hip/hip_runtime.h>
#include <hip/hip_bf16.h>

// ---------------------------------------------------------------------------
// Phase 1a: CSR build by dst, then gather-aggregate
// ---------------------------------------------------------------------------

__global__ __launch_bounds__(256) void sge_count(
    const int* __restrict__ dst, int* __restrict__ cnt, int nE) {
  int e = blockIdx.x * 256 + threadIdx.x;
  if (e >= nE) return;
  atomicAdd(&cnt[dst[e]], 1);
}

__global__ __launch_bounds__(256) void sge_blocksum(
    const int* __restrict__ cnt, int* __restrict__ bsum, int N) {
  int i = blockIdx.x * 256 + threadIdx.x;
  int v = (i < N) ? cnt[i] : 0;
#pragma unroll
  for (int o = 1; o < 64; o <<= 1) v += __shfl_xor(v, o);
  __shared__ int ws[4];
  int lane = threadIdx.x & 63, wid = threadIdx.x >> 6;
  if (lane == 0) ws[wid] = v;
  __syncthreads();
  if (threadIdx.x == 0)
    bsum[blockIdx.x] = ws[0] + ws[1] + ws[2] + ws[3];
}

__global__ __launch_bounds__(64) void sge_scan_top(
    int* __restrict__ bsum, int* __restrict__ offs, int nb, int N, int nE) {
  int lane = threadIdx.x;
  int carry = 0;
  for (int base = 0; base < nb; base += 64) {
    int i = base + lane;
    int v = (i < nb) ? bsum[i] : 0;
    int s = v;
#pragma unroll
    for (int o = 1; o < 64; o <<= 1) {
      int t = __shfl_up(s, o);
      if (lane >= o) s += t;
    }
    if (i < nb) bsum[i] = carry + s - v;  // exclusive
    carry += __shfl(s, 63);
  }
  if (lane == 0) offs[N] = nE;
}

__global__ __launch_bounds__(256) void sge_scan_block(
    const int* __restrict__ cnt, const int* __restrict__ bsum,
    int* __restrict__ offs, int* __restrict__ pos, int N) {
  int i = blockIdx.x * 256 + threadIdx.x;
  int v = (i < N) ? cnt[i] : 0;
  int lane = threadIdx.x & 63, wid = threadIdx.x >> 6;
  int s = v;
#pragma unroll
  for (int o = 1; o < 64; o <<= 1) {
    int t = __shfl_up(s, o);
    if (lane >= o) s += t;
  }
  __shared__ int ws[4];
  if (lane == 63) ws[wid] = s;
  __syncthreads();
  int wbase = 0;
  for (int w = 0; w < wid; ++w) wbase += ws[w];
  if (i < N) {
    int o = bsum[blockIdx.x] + wbase + s - v;
    offs[i] = o;
    pos[i] = o;
  }
}

__global__ __launch_bounds__(256) void sge_fill(
    const int* __restrict__ src, const int* __restrict__ dst,
    int* __restrict__ pos, int* __restrict__ sorted_src, int nE) {
  int e = blockIdx.x * 256 + threadIdx.x;
  if (e >= nE) return;
  int p = atomicAdd(&pos[dst[e]], 1);
  sorted_src[p] = src[e];
}

// 32 lanes per node, float4 per lane, 8 nodes per block, 4-way unroll
__global__ __launch_bounds__(256) void sge_gather(
    const float* __restrict__ x, const int* __restrict__ sorted_src,
    const int* __restrict__ offs, float* __restrict__ agg, int N) {
  int node = blockIdx.x * 8 + (threadIdx.x >> 5);
  int c4 = (threadIdx.x & 31) << 2;
  if (node >= N) return;
  int e0 = offs[node], e1 = offs[node + 1];
  float4 A = {0.f, 0.f, 0.f, 0.f}, B = {0.f, 0.f, 0.f, 0.f};
  float4 Cc = {0.f, 0.f, 0.f, 0.f}, D = {0.f, 0.f, 0.f, 0.f};
  int e = e0;
  for (; e + 4 <= e1; e += 4) {
    int s0 = sorted_src[e];
    int s1 = sorted_src[e + 1];
    int s2 = sorted_src[e + 2];
    int s3 = sorted_src[e + 3];
    float4 v0 = *(const float4*)&x[(size_t)s0 * 128 + c4];
    float4 v1 = *(const float4*)&x[(size_t)s1 * 128 + c4];
    float4 v2 = *(const float4*)&x[(size_t)s2 * 128 + c4];
    float4 v3 = *(const float4*)&x[(size_t)s3 * 128 + c4];
    A.x += v0.x; A.y += v0.y; A.z += v0.z; A.w += v0.w;
    B.x += v1.x; B.y += v1.y; B.z += v1.z; B.w += v1.w;
    Cc.x += v2.x; Cc.y += v2.y; Cc.z += v2.z; Cc.w += v2.w;
    D.x += v3.x; D.y += v3.y; D.z += v3.z; D.w += v3.w;
  }
  for (; e < e1; ++e) {
    float4 v0 = *(const float4*)&x[(size_t)sorted_src[e] * 128 + c4];
    A.x += v0.x; A.y += v0.y; A.z += v0.z; A.w += v0.w;
  }
  float inv = 1.0f / fmaxf((float)(e1 - e0), 1.0f);
  float4 r;
  r.x = ((A.x + B.x) + (Cc.x + D.x)) * inv;
  r.y = ((A.y + B.y) + (Cc.y + D.y)) * inv;
  r.z = ((A.z + B.z) + (Cc.z + D.z)) * inv;
  r.w = ((A.w + B.w) + (Cc.w + D.w)) * inv;
  *(float4*)&agg[(size_t)node * 128 + c4] = r;
}

// ---------------------------------------------------------------------------
// Phase 1b: z = agg @ W   [N,128]@[128,256] -> [N,256]
// ---------------------------------------------------------------------------
__global__ __launch_bounds__(256) void sge_gemm(
    const float* __restrict__ agg, const float* __restrict__ W,
    float* __restrict__ z) {
  __shared__ float xs[32][128];
  int n0 = blockIdx.x * 32;
  int t = threadIdx.x;
#pragma unroll
  for (int i = 0; i < 16; ++i) {
    int idx = t + i * 256;
    int r = idx >> 7;
    int c = idx & 127;
    xs[r][c] = agg[(long long)(n0 + r) * 128 + c];
  }
  __syncthreads();
  int wv = t >> 6, lane = t & 63;
  int r0 = wv * 8;
  float acc[8][4];
#pragma unroll
  for (int r = 0; r < 8; ++r)
#pragma unroll
    for (int q = 0; q < 4; ++q) acc[r][q] = 0.f;
  for (int k = 0; k < 128; k += 4) {
    float4 xv[8];
#pragma unroll
    for (int r = 0; r < 8; ++r) xv[r] = *(const float4*)&xs[r0 + r][k];
#pragma unroll
    for (int kk = 0; kk < 4; ++kk) {
      const float* Wr = W + (k + kk) * 256 + lane;
      float w0 = Wr[0], w1 = Wr[64], w2 = Wr[128], w3 = Wr[192];
#pragma unroll
      for (int r = 0; r < 8; ++r) {
        float xk = (kk == 0) ? xv[r].x
                 : (kk == 1) ? xv[r].y
                 : (kk == 2) ? xv[r].z : xv[r].w;
        acc[r][0] = fmaf(xk, w0, acc[r][0]);
        acc[r][1] = fmaf(xk, w1, acc[r][1]);
        acc[r][2] = fmaf(xk, w2, acc[r][2]);
        acc[r][3] = fmaf(xk, w3, acc[r][3]);
      }
    }
  }
#pragma unroll
  for (int r = 0; r < 8; ++r) {
    float* zr = z + (long long)(n0 + r0 + r) * 256 + lane;
#pragma unroll
    for (int q = 0; q < 4; ++q) zr[q * 64] = acc[r][q];
  }
}

// ---------------------------------------------------------------------------
// Phase 2 (v14): v13 + norm-form build (12 ops/entry vs 17; norms exchanged
// via per-wave LDS, broadcast reads). Build VALU -40%.
// ---------------------------------------------------------------------------
template <int CTRL>
__device__ __forceinline__ float dpp_max(float x) {
  int r = __builtin_amdgcn_update_dpp(__float_as_int(x), __float_as_int(x),
                                      CTRL, 0xF, 0xF, false);
  return fmaxf(x, __int_as_float(r));
}
template <int CTRL>
__device__ __forceinline__ float dpp_add(float x) {
  int r = __builtin_amdgcn_update_dpp(0, __float_as_int(x), CTRL, 0xF, 0xF, true);
  return x + __int_as_float(r);
}

__global__ __launch_bounds__(256, 4) void sge_energy(
    const float* __restrict__ z, const int* __restrict__ ep,
    const int* __restrict__ en, float* __restrict__ partial, int nP) {
  __shared__ __align__(16) float Ebuf[2][2][64];  // [pair][wave][64]
  __shared__ __align__(16) float Nbuf[2][2][64];  // [pair][wave][64] norms
  __shared__ float red[2][2];

  int t = threadIdx.x;
  int pl = t >> 7;        // pair-local index 0/1
  int tp = t & 127;       // thread within pair
  int w = tp >> 6;        // wave-in-pair: 0={xy,yx}, 1={xx,yy}
  int l = tp & 63;
  int row = l & 31;
  int own = l & 32;       // 0 = x-rows half, 32 = y-rows half

  int pair = blockIdx.x * 2 + pl;
  bool isPos = pair < nP;
  int idx = isPos ? pair : pair - nP;
  const int* E = isPos ? ep : en;
  int na = E[idx], nb = E[idx + nP];

  // own row straight from global
  const float* zrow = z + (size_t)(own ? nb : na) * 256 + row * 8;
  float4 r0 = ((const float4*)zrow)[0];
  float4 r1 = ((const float4*)zrow)[1];
  float xr[8];
  xr[0] = r0.x; xr[1] = r0.y; xr[2] = r0.z; xr[3] = r0.w;
  xr[4] = r1.x; xr[5] = r1.y; xr[6] = r1.z; xr[7] = r1.w;

  // own squared norm -> LDS exchange (same rb addressing as Ebuf)
  float nself = xr[0] * xr[0];
  nself = fmaf(xr[1], xr[1], nself); nself = fmaf(xr[2], xr[2], nself);
  nself = fmaf(xr[3], xr[3], nself); nself = fmaf(xr[4], xr[4], nself);
  nself = fmaf(xr[5], xr[5], nself); nself = fmaf(xr[6], xr[6], nself);
  nself = fmaf(xr[7], xr[7], nself);
  Nbuf[pl][w][l] = nself;
  __builtin_amdgcn_wave_barrier();

  bool colIsX = (w == 0) ? (own != 0) : (own == 0);
  const float4* zc = (const float4*)(z + (size_t)(colIsX ? na : nb) * 256);
  int rb = (w == 0) ? (own ^ 32) : own;
  const float* Nw = Nbuf[pl][w] + rb;

  const float RLNE = 1.44269504088896340736f;  // log2(e)
  const float LN2 = 0.69314718055994530942f;
  const float LN32 = 3.46573590279972654709f;  // ln(32)
  const float K20 = RLNE / 10.0f;
  const float NK28 = -RLNE / 0.05f;            // -k2 at final eps

  // build C (kept) and V = 2^(-C*k2_0); norm-form distance
  float C[32], V[32];
#pragma unroll
  for (int jq = 0; jq < 8; ++jq) {
    float4 nj4 = ((const float4*)Nw)[jq];
    float4 a[8];
#pragma unroll
    for (int k = 0; k < 4; ++k) {
      a[2 * k] = zc[8 * jq + 2 * k];
      a[2 * k + 1] = zc[8 * jq + 2 * k + 1];
    }
#pragma unroll
    for (int k = 0; k < 4; ++k) {
      int j = jq * 4 + k;
      float4 a0 = a[2 * k], a1 = a[2 * k + 1];
      float d = xr[0] * a0.x;
      d = fmaf(xr[1], a0.y, d); d = fmaf(xr[2], a0.z, d);
      d = fmaf(xr[3], a0.w, d); d = fmaf(xr[4], a1.x, d);
      d = fmaf(xr[5], a1.y, d); d = fmaf(xr[6], a1.z, d);
      d = fmaf(xr[7], a1.w, d);
      float nj = (k == 0) ? nj4.x : (k == 1) ? nj4.y : (k == 2) ? nj4.z : nj4.w;
      float sq = fmaf(-2.0f, d, nself + nj);
      float Cv = __builtin_amdgcn_sqrtf(fmaxf(sq, 0.0f) + 1e-8f);
      C[j] = Cv;
      V[j] = __builtin_amdgcn_exp2f(-Cv * K20);
    }
  }

  float* Ew = Ebuf[pl][w];

  float P = 0.0f;
  float epsv = 10.0f;

#pragma unroll 1
  for (int it = 0; it < 9; ++it) {
    float eps = (it == 8) ? 0.05f : epsv;
    float k2 = RLNE / eps;
    float eln2 = eps * LN2;
    float c32 = eps * LN32;

    if (it == 8) {
#pragma unroll
      for (int j = 0; j < 32; ++j)
        V[j] = __builtin_amdgcn_exp2f(C[j] * NK28);
    } else if (it > 0) {
#pragma unroll
      for (int j = 0; j < 32; ++j) V[j] *= V[j];
    }

    float mOwn, mRead;
    if (it >= 7) {
      float m = P;
      m = dpp_max<0x111>(m);
      m = dpp_max<0x112>(m);
      m = dpp_max<0x114>(m);
      m = dpp_max<0x118>(m);
      m = dpp_max<0x142>(m);  // lanes 31/63 hold half maxes
      float g0 = __int_as_float(__builtin_amdgcn_readlane(__float_as_int(m), 31));
      float g1 = __int_as_float(__builtin_amdgcn_readlane(__float_as_int(m), 63));
      mOwn = own ? g1 : g0;
      mRead = (w == 0) ? (own ? g0 : g1) : mOwn;
    } else {
      mOwn = 0.0f;
      mRead = 0.0f;
    }

    Ew[l] = __builtin_amdgcn_exp2f((P - mOwn) * k2);
    __builtin_amdgcn_wave_barrier();

    float s0 = 0.f, s1 = 0.f, s2 = 0.f, s3 = 0.f;
#pragma unroll
    for (int jq = 0; jq < 8; ++jq) {
      float4 Ev = ((const float4*)(Ew + rb))[jq];
      s0 = fmaf(Ev.x, V[4 * jq + 0], s0);
      s1 = fmaf(Ev.y, V[4 * jq + 1], s1);
      s2 = fmaf(Ev.z, V[4 * jq + 2], s2);
      s3 = fmaf(Ev.w, V[4 * jq + 3], s3);
    }
    float s = fmaxf((s0 + s1) + (s2 + s3), 1e-37f);
    __builtin_amdgcn_wave_barrier();  // reads complete before next write

    P = 0.5f * (P + (c32 - mRead - eln2 * __builtin_amdgcn_logf(s)));
    epsv *= 0.5f;
  }

  // wave sums via DPP
  float d = P;
  d = dpp_add<0x111>(d);
  d = dpp_add<0x112>(d);
  d = dpp_add<0x114>(d);
  d = dpp_add<0x118>(d);
  d = dpp_add<0x142>(d);
  float s31 = __int_as_float(__builtin_amdgcn_readlane(__float_as_int(d), 31));
  float s63 = __int_as_float(__builtin_amdgcn_readlane(__float_as_int(d), 63));
  if (l == 0) red[pl][w] = s31 + s63;
  __syncthreads();
  if (t == 0) {
    float tot = 0.0f;
#pragma unroll
    for (int q = 0; q < 2; ++q) {
      int pr = blockIdx.x * 2 + q;
      float e = (red[q][0] - red[q][1]) * (1.0f / 32.0f);
      float term;
      if (pr < nP) {
        term = e * e;
      } else {
        float mm = fmaxf(1.0f - e, 0.0f);
        term = mm * mm;
      }
      tot += term;
    }
    partial[blockIdx.x] = tot;   // no atomics: per-block partial
  }
}

// single-block final reduction: out = sum(partial) / nP
__global__ __launch_bounds__(1024) void sge_reduce(
    const float* __restrict__ partial, int n, float invnP,
    float* __restrict__ out) {
  __shared__ float ws[16];
  float s = 0.0f;
  for (int i = threadIdx.x; i < n; i += 1024) s += partial[i];
#pragma unroll
  for (int o = 1; o < 64; o <<= 1) s += __shfl_xor(s, o);
  if ((threadIdx.x & 63) == 0) ws[threadIdx.x >> 6] = s;
  __syncthreads();
  if (threadIdx.x == 0) {
    float tt = 0.0f;
#pragma unroll
    for (int q = 0; q < 16; ++q) tt += ws[q];
    out[0] = tt * invnP;
  }
}

// ---------------------------------------------------------------------------
extern "C" void kernel_launch(void* const* d_in, const int* in_sizes, int n_in,
                              void* d_out, int out_size, void* d_ws, size_t ws_size,
                              hipStream_t stream) {
  const float* x  = (const float*)d_in[0];
  const int*   ei = (const int*)d_in[1];
  const int*   ep = (const int*)d_in[2];
  const int*   en = (const int*)d_in[3];
  const float* W  = (const float*)d_in[4];
  float* out = (float*)d_out;

  int N  = in_sizes[0] / 128;   // 100000 nodes
  int nE = in_sizes[1] / 2;     // 1600000 edges
  int nP = in_sizes[2] / 2;     // 30000 pos (== neg)

  size_t zBytes   = (size_t)N * 256 * sizeof(float);
  size_t aggBytes = (size_t)N * 128 * sizeof(float);
  if (ws_size < zBytes + aggBytes) return;

  char* ws = (char*)d_ws;
  float* z   = (float*)ws;                 // written LAST (by gemm)
  float* agg = (float*)(ws + zBytes);

  // CSR temporaries overlaid inside the z region (dead before gemm)
  int* cnt        = (int*)ws;              // N
  int* offs       = cnt + N;               // N+1
  int* pos        = offs + N + 1;          // N
  int* bsum       = pos + N;               // <= 4096
  int* sorted_src = bsum + 4096;           // nE

  // per-block partials overlaid in the agg region (dead after gemm)
  float* partial = agg;                    // nP floats

  int nb = (N + 255) / 256;

  hipMemsetAsync(cnt, 0, (size_t)N * sizeof(int), stream);

  const int* src = ei;
  const int* dst = ei + nE;

  int eb = (nE + 255) / 256;
  sge_count<<<eb, 256, 0, stream>>>(dst, cnt, nE);
  sge_blocksum<<<nb, 256, 0, stream>>>(cnt, bsum, N);
  sge_scan_top<<<1, 64, 0, stream>>>(bsum, offs, nb, N, nE);
  sge_scan_block<<<nb, 256, 0, stream>>>(cnt, bsum, offs, pos, N);
  sge_fill<<<eb, 256, 0, stream>>>(src, dst, pos, sorted_src, nE);
  sge_gather<<<(N + 7) / 8, 256, 0, stream>>>(x, sorted_src, offs, agg, N);

  sge_gemm<<<(N + 31) / 32, 256, 0, stream>>>(agg, W, z);

  sge_energy<<<nP, 256, 0, stream>>>(z, ep, en, partial, nP);
  sge_reduce<<<1, 1024, 0, stream>>>(partial, nP, 1.0f / (float)nP, out);
}